// Round 11
// baseline (123.329 us; speedup 1.0000x reference)
//
#include <hip/hip_runtime.h>
#include <hip/hip_bf16.h>
#include <math.h>

// N=64, C=512, T=64, P=2016
// 3-kernel pipeline:
//  k_prep  (1025): Wbf (fragment-packed bf16 W') | Gb+Ab | xxTf | score_part
//  k_fgemm (64,5,4): G[n] = W' @ x[n] + Gb -> FTf/ALf, PAIR-fragment-packed bf16
//  k_pairs (504 x 4 waves): wave-per-pair MFMA GEMM + in-register pool1 +
//           wave-local conv2/pool2/fc tail, ZERO barriers + fused sigmoid
// Pair-fragment packing (mfma_16x16x32_bf16, lane l = kgrp*16 + l15):
//   ALf[i] 8KB:  ((oa*4+ks)*64 + l)*8 + u  = A[oa*16+l15][ks*32+kgrp*8+u]
//   FTf[j] 32KB: ((et*4+ks)*64 + l)*8 + u  = B[ks*32+kgrp*8+u][et*16+l15]
//   (B[k][e] = f[j][(k>>6)*128+e][k&63];  A from W' rows 256..319)
// ws: xxTf 4MB | FTf 2MB | ALf 512KB | Wbf 320KB | Gb/part ~3KB  (~6.8 MB)

typedef __attribute__((ext_vector_type(8))) short short8;
typedef __attribute__((ext_vector_type(4))) float f32x4;

__device__ __forceinline__ unsigned short f2bf(float f) {
    __hip_bfloat16 h = __float2bfloat16(f);   // RNE
    return *reinterpret_cast<unsigned short*>(&h);
}

// ---------------- k_prep: all independent prep in one launch ----------------
__global__ __launch_bounds__(256) void k_prep(
    const float* __restrict__ x, const float* __restrict__ w_conv1d,
    const float* __restrict__ b_conv1d, const float* __restrict__ w_c1,
    const float* __restrict__ w_mlp,
    unsigned short* __restrict__ xxTf, unsigned short* __restrict__ Wbf,
    float* __restrict__ Gb, float* __restrict__ part)
{
    __shared__ float sf[64 * 65];      // xprep tile / abred / red
    int u = blockIdx.x, tid = threadIdx.x;

    if (u < 128) {
        // Wbf rows 0..255: bf16 convert, 4 floats/thread, packed store
        int idx = u * 256 + tid;
        int m = idx >> 7, c4 = (idx & 127) * 4;
        float4 v = *reinterpret_cast<const float4*>(w_conv1d + m * 512 + c4);
        ushort4 uu;
        uu.x = f2bf(v.x); uu.y = f2bf(v.y); uu.z = f2bf(v.z); uu.w = f2bf(v.w);
        int mt = m >> 4, r15 = m & 15;
        int kc = c4 >> 5, k8 = (c4 >> 3) & 3, rem = c4 & 7;
        *reinterpret_cast<ushort4*>(
            Wbf + ((mt * 16 + kc) * 64 + k8 * 16 + r15) * 8 + rem) = uu;
    } else if (u < 256) {
        // Wa[r][cin] -> Wbf rows 256..319; q-split + ordered sum
        int b = u - 128;
        int r = b >> 1;
        int cin = (b & 1) * 256 + tid;
        int s = r >> 5, o = r & 31;
        const float* wrow = w_c1 + o * 512 + s;
        const float* wcp  = w_conv1d + cin;
        float pq[4];
        #pragma unroll
        for (int q = 0; q < 4; ++q) {
            float acc = 0.f;
            #pragma unroll 8
            for (int c = q * 64; c < q * 64 + 64; ++c)
                acc += wrow[2 * c] * wcp[c * 512];
            pq[q] = acc;
        }
        float v = ((pq[0] + pq[1]) + pq[2]) + pq[3];
        int m = 256 + r;
        int mt = m >> 4, r15 = m & 15;
        int kc = cin >> 5, k8 = (cin >> 3) & 3, rem = cin & 7;
        Wbf[((mt * 16 + kc) * 64 + k8 * 16 + r15) * 8 + rem] = f2bf(v);
    } else if (u == 256) {
        // Gb bias + Ab
        float* abred = sf;
        Gb[tid] = b_conv1d[tid];
        int r = tid & 63, q = tid >> 6;
        int s = r >> 5, o = r & 31;
        const float* wr2 = w_c1 + o * 512 + s;
        float a = 0.f;
        #pragma unroll 8
        for (int c = q * 64; c < q * 64 + 64; ++c)
            a += wr2[2 * c] * b_conv1d[c];
        abred[tid] = a;
        __syncthreads();
        if (tid < 64)
            Gb[256 + tid] = abred[tid] + abred[tid + 64]
                          + abred[tid + 128] + abred[tid + 192];
    } else if (u < 769) {
        // xprep: transpose then packed bf16 store
        int v = u - 257;
        int n = v >> 3, c0 = (v & 7) * 64;
        float* tile = sf;                  // [64][65]
        int cl = tid >> 4, t4 = (tid & 15) * 4;
        const float* xp = x + n * 32768 + c0 * 64;
        #pragma unroll
        for (int pp = 0; pp < 4; ++pp) {
            int c = cl + pp * 16;
            float4 vv = *reinterpret_cast<const float4*>(xp + c * 64 + t4);
            tile[(t4 + 0) * 65 + c] = vv.x; tile[(t4 + 1) * 65 + c] = vv.y;
            tile[(t4 + 2) * 65 + c] = vv.z; tile[(t4 + 3) * 65 + c] = vv.w;
        }
        __syncthreads();
        int tl = tid >> 4, cl4 = (tid & 15) * 4;
        int c = c0 + cl4;
        int kc = c >> 5, k8 = (c >> 3) & 3, rem = c & 7;
        #pragma unroll
        for (int pp = 0; pp < 4; ++pp) {
            int t = tl + pp * 16;          // tt = pp, r15 = tl
            ushort4 uu;
            uu.x = f2bf(tile[t * 65 + cl4 + 0]);
            uu.y = f2bf(tile[t * 65 + cl4 + 1]);
            uu.z = f2bf(tile[t * 65 + cl4 + 2]);
            uu.w = f2bf(tile[t * 65 + cl4 + 3]);
            *reinterpret_cast<ushort4*>(
                xxTf + n * 32768 + ((pp * 16 + kc) * 64 + k8 * 16 + tl) * 8 + rem) = uu;
        }
    } else {
        // score_part
        int v = u - 769;
        int n = v >> 2, c4 = v & 3;
        const float4* x4 = reinterpret_cast<const float4*>(x + n * 32768) + c4 * 2048;
        const float4* w4 = reinterpret_cast<const float4*>(w_mlp) + c4 * 2048;
        float acc = 0.f;
        for (int uu = tid; uu < 2048; uu += 256) {
            float4 a = x4[uu], w = w4[uu];
            acc += a.x * w.x + a.y * w.y + a.z * w.z + a.w * w.w;
        }
        for (int off = 32; off; off >>= 1) acc += __shfl_down(acc, off, 64);
        float* red = sf;
        if ((tid & 63) == 0) red[tid >> 6] = acc;
        __syncthreads();
        if (tid == 0)
            part[n * 4 + c4] = red[0] + red[1] + red[2] + red[3];
    }
}

// ---------------- k_fgemm: G = W' @ x + Gb -> FTf / ALf (pair-packed bf16) --
// grid (64 n, 5 mg, 4 nt); wave w: m-tile mt = mg*4+w, t-tile tt = nt
__global__ __launch_bounds__(256) void k_fgemm(
    const unsigned short* __restrict__ Wbf, const unsigned short* __restrict__ xxTf,
    const float* __restrict__ Gb, unsigned short* __restrict__ FTf,
    unsigned short* __restrict__ ALf)
{
    int n = blockIdx.x, mg = blockIdx.y, nt = blockIdx.z;
    int tid = threadIdx.x, l = tid & 63, w = tid >> 6;
    int mt = mg * 4 + w;
    int m0 = mt * 16;
    int t0 = nt * 16;
    int r15 = l & 15, kg = l >> 4;
    const unsigned short* ap = Wbf + (size_t)mt * 16 * 512 + l * 8;
    const unsigned short* bp = xxTf + (size_t)n * 32768 + (size_t)nt * 16 * 512 + l * 8;
    f32x4 acc = {0.f, 0.f, 0.f, 0.f};
    #pragma unroll
    for (int ks = 0; ks < 16; ++ks) {
        short8 a = *reinterpret_cast<const short8*>(ap + ks * 512);
        short8 b = *reinterpret_cast<const short8*>(bp + ks * 512);
        acc = __builtin_amdgcn_mfma_f32_16x16x32_bf16(a, b, acc, 0, 0, 0);
    }
    // D: col = l&15 -> t, row = (l>>4)*4 + reg -> m   [m89-verified]
    int t = t0 + r15;
    int mrow = m0 + kg * 4;
    float4 gb = *reinterpret_cast<const float4*>(Gb + mrow);
    float gbv[4] = {gb.x, gb.y, gb.z, gb.w};
    int ksl = t >> 5, kgrp = (t >> 3) & 3, uu = t & 7;   // r-independent parts
    if (m0 < 256) {
        #pragma unroll
        for (int r = 0; r < 4; ++r) {
            int m = mrow + r;
            int e = m & 127, s = m >> 7;
            int et = e >> 4, l15 = e & 15;
            int ks = s * 2 + ksl;
            FTf[n * 16384 + ((et * 4 + ks) * 64 + kgrp * 16 + l15) * 8 + uu]
                = f2bf(acc[r] + gbv[r]);
        }
    } else {
        #pragma unroll
        for (int r = 0; r < 4; ++r) {
            int m = mrow + r;
            int rr = m - 256, o = rr & 31, sA = rr >> 5;
            int oa = o >> 4, l15 = o & 15;
            int ks = sA * 2 + ksl;
            ALf[n * 4096 + ((oa * 4 + ks) * 64 + kgrp * 16 + l15) * 8 + uu]
                = f2bf(acc[r] + gbv[r]);
        }
    }
}

// ---------------- k_pairs: wave-per-pair, zero barriers ----------------
// grid 504 x 256; wave w handles pair wp = bid*4+w
__global__ __launch_bounds__(256) void k_pairs(
    const unsigned short* __restrict__ FTf, const unsigned short* __restrict__ ALf,
    const float* __restrict__ b_c1, const float* __restrict__ w_c2,
    const float* __restrict__ b_c2, const float* __restrict__ w_fc1,
    const float* __restrict__ b_fc1, const float* __restrict__ w_fc2,
    const float* __restrict__ b_fc2, const float* __restrict__ w_fc3,
    const float* __restrict__ b_fc3, const float* __restrict__ part,
    const float* __restrict__ bm, float* __restrict__ out)
{
    __shared__ float sm[4 * 1440];     // per-wave slice: PL 1056 | C2 264 | V 64 | R1 32 | R2 8
    int tid = threadIdx.x, w = tid >> 6, l = tid & 63;
    int wp = blockIdx.x * 4 + w;       // pair id, 2016 = 504*4 exact

    // fused score head: block 0 wave 0 (extra work, no divergence hazard)
    if (blockIdx.x == 0 && w == 0) {
        int n = l;
        float s = part[n * 4] + part[n * 4 + 1] + part[n * 4 + 2]
                + part[n * 4 + 3] + bm[0];
        out[n] = 1.f / (1.f + expf(-s));
    }

    int i = 0, rem = wp;
    while (rem >= 63 - i) { rem -= 63 - i; ++i; }
    int j = i + 1 + rem;

    const unsigned short* ap = ALf + i * 4096;
    const unsigned short* bp = FTf + (size_t)j * 16384;

    f32x4 acc[2][8] = {};
    #pragma unroll
    for (int ks = 0; ks < 4; ++ks) {
        short8 a0 = *reinterpret_cast<const short8*>(ap + ((0 + ks) * 64 + l) * 8);
        short8 a1 = *reinterpret_cast<const short8*>(ap + ((4 + ks) * 64 + l) * 8);
        #pragma unroll
        for (int et = 0; et < 8; ++et) {
            short8 b = *reinterpret_cast<const short8*>(bp + ((et * 4 + ks) * 64 + l) * 8);
            acc[0][et] = __builtin_amdgcn_mfma_f32_16x16x32_bf16(a0, b, acc[0][et], 0, 0, 0);
            acc[1][et] = __builtin_amdgcn_mfma_f32_16x16x32_bf16(a1, b, acc[1][et], 0, 0, 0);
        }
    }

    float* PL = sm + w * 1440;         // [32][33] pooled + bias
    float* C2 = PL + 1056;             // [8][33]
    float* V  = C2 + 264;              // 64
    float* R1 = V + 64;                // 32
    float* R2 = R1 + 32;               // 8

    int c = l & 15, g = l >> 4;
    // D layout: row o = oa*16 + g*4 + r, col e = et*16 + c   [m89-verified]
    // in-register pool1: max over lanes {c, c^1, c^4, c^5} == e-group {e0,e0+1,e0+4,e0+5}
    bool valid = (c == 0) | (c == 2) | (c == 8) | (c == 10);
    int phb = ((c >> 3) << 1) + ((c >> 1) & 1);    // 0,1,2,3 for c=0,2,8,10
    float bc[2][4];
    #pragma unroll
    for (int oa = 0; oa < 2; ++oa)
        #pragma unroll
        for (int r = 0; r < 4; ++r) bc[oa][r] = b_c1[oa * 16 + g * 4 + r];
    #pragma unroll
    for (int oa = 0; oa < 2; ++oa)
        #pragma unroll
        for (int et = 0; et < 8; ++et)
            #pragma unroll
            for (int r = 0; r < 4; ++r) {
                float v = acc[oa][et][r];
                v = fmaxf(v, __shfl_xor(v, 1, 64));
                v = fmaxf(v, __shfl_xor(v, 4, 64));
                if (valid) {
                    int o = oa * 16 + g * 4 + r;
                    PL[o * 33 + et * 4 + phb] = v + bc[oa][r];
                }
            }
    // wave-local LDS: no barrier needed (same-wave deps ordered via lgkmcnt)

    // conv2: 4 outputs/lane
    #pragma unroll
    for (int q = 0; q < 4; ++q) {
        int idx = q * 64 + l;
        int o2 = idx >> 5, pos = idx & 31;
        float a2 = b_c2[o2];
        #pragma unroll 8
        for (int o = 0; o < 32; ++o) a2 += w_c2[o2 * 32 + o] * PL[o * 33 + pos];
        C2[o2 * 33 + pos] = a2;
    }

    // pool2: 1 output/lane
    {
        int o2 = l >> 3, h3 = l & 7;
        const float* cp = C2 + o2 * 33 + h3 * 4;
        V[l] = fmaxf(fmaxf(cp[0], cp[1]), fmaxf(cp[2], cp[3]));
    }

    if (l < 32) {
        float a = b_fc1[l];
        const float* wr = w_fc1 + l * 64;
        #pragma unroll 8
        for (int u = 0; u < 64; ++u) a += wr[u] * V[u];
        R1[l] = fmaxf(a, 0.f);
    }
    if (l < 8) {
        float a = b_fc2[l];
        #pragma unroll 8
        for (int u = 0; u < 32; ++u) a += w_fc2[l * 32 + u] * R1[u];
        R2[l] = fmaxf(a, 0.f);
    }
    if (l == 0) {
        float a = b_fc3[0];
        #pragma unroll
        for (int u = 0; u < 8; ++u) a += w_fc3[u] * R2[u];
        out[64 + wp] = 1.f / (1.f + expf(-a));
    }
}

extern "C" void kernel_launch(void* const* d_in, const int* in_sizes, int n_in,
                              void* d_out, int out_size, void* d_ws, size_t ws_size,
                              hipStream_t stream) {
    const float* x        = (const float*)d_in[0];
    const float* w_conv1d = (const float*)d_in[1];
    const float* b_conv1d = (const float*)d_in[2];
    const float* w_c1     = (const float*)d_in[3];
    const float* b_c1     = (const float*)d_in[4];
    const float* w_c2     = (const float*)d_in[5];
    const float* b_c2     = (const float*)d_in[6];
    const float* w_fc1    = (const float*)d_in[7];
    const float* b_fc1    = (const float*)d_in[8];
    const float* w_fc2    = (const float*)d_in[9];
    const float* b_fc2    = (const float*)d_in[10];
    const float* w_fc3    = (const float*)d_in[11];
    const float* b_fc3    = (const float*)d_in[12];
    const float* w_mlp    = (const float*)d_in[13];
    const float* b_mlp    = (const float*)d_in[14];
    float* out = (float*)d_out;

    char* base = (char*)d_ws;
    unsigned short* xxTf = (unsigned short*)(base);                  // 4 MB
    unsigned short* FTf  = (unsigned short*)(base + 4194304);        // 2 MB
    unsigned short* ALf  = (unsigned short*)(base + 6291456);        // 512 KB
    unsigned short* Wbf  = (unsigned short*)(base + 6815744);        // 320 KB
    float*          Gb   = (float*)(base + 7143424);                 // 1280 B
    float*          part = (float*)(base + 7145472);                 // 1 KB
    // total ~6.8 MB (9 MB proven safe)

    hipLaunchKernelGGL(k_prep, dim3(1025), dim3(256), 0, stream,
                       x, w_conv1d, b_conv1d, w_c1, w_mlp,
                       xxTf, Wbf, Gb, part);
    hipLaunchKernelGGL(k_fgemm, dim3(64, 5, 4), dim3(256), 0, stream,
                       Wbf, xxTf, Gb, FTf, ALf);
    hipLaunchKernelGGL(k_pairs, dim3(504), dim3(256), 0, stream,
                       FTf, ALf, b_c1, w_c2, b_c2, w_fc1, b_fc1,
                       w_fc2, b_fc2, w_fc3, b_fc3, part, b_mlp, out);
}